// Round 13
// baseline (5544.154 us; speedup 1.0000x reference)
//
#include <hip/hip_runtime.h>

namespace {

typedef _Float16 __attribute__((ext_vector_type(2))) h2v;   // one VGPR = 2 f16

constexpr int KST = 1024;
constexpr size_t OFF_R = (size_t)512 * KST * 5;
constexpr size_t OFF_D = OFF_R + (size_t)512 * KST * 8;

__device__ __forceinline__ float sigf(float x) { return 1.0f / (1.0f + __expf(-x)); }
__device__ __forceinline__ float tanhfast(float x) {
    float e2 = __expf(2.0f * x);
    return 1.0f - 2.0f / (e2 + 1.0f);
}
__device__ __forceinline__ float fdot2(h2v a, h2v b, float c) {
    return __builtin_amdgcn_fdot2(a, b, c, false);
}
// DPP lane shifts within 16-lane rows (0-fill at edges) — state-per-lane RK4.
__device__ __forceinline__ float dpp_shr1(float v) {   // lane i <- lane i-1
    return __builtin_bit_cast(float, __builtin_amdgcn_update_dpp(
        0, __builtin_bit_cast(int, v), 0x111, 0xf, 0xf, true));
}
__device__ __forceinline__ float dpp_shl1(float v) {   // lane i <- lane i+1
    return __builtin_bit_cast(float, __builtin_amdgcn_update_dpp(
        0, __builtin_bit_cast(int, v), 0x101, 0xf, 0xf, true));
}

// v13 = v11 numerics (bit-identical per-row) restructured for CO-RESIDENCY:
// 1 batch row per WG, 512 WGs, 384 threads. Register budget law (r1-r6):
// (384,2) -> 128 VGPRs; full-row f16-packed hi weights = 96 pinned regs fit.
// LDS ~63KB -> exactly 2 WGs/CU (160KB limit); 2 WGs x 6 waves = 12 waves/CU
// from two INDEPENDENT barrier groups -> one WG's latency stalls (LDS round
// trips, wave-0 serial tail) are filled by the other WG's compute. v11 was
// 1 WG/CU, VALUBusy 39%, 60% idle — that idle is the target.
__global__ __launch_bounds__(384, 2) void rnn_v13(
    const float* __restrict__ y0,     const float* __restrict__ u_seq,
    const float* __restrict__ dt_seq, const float* __restrict__ W_lift,
    const float* __restrict__ b_lift, const float* __restrict__ W_ih,
    const float* __restrict__ W_hh,   const float* __restrict__ b_ih,
    const float* __restrict__ b_hh,   const float* __restrict__ W_head,
    const float* __restrict__ b_head, const float* __restrict__ u2y,
    float* __restrict__ out)
{
    const int t    = threadIdx.x;        // 0..383 ; owns GRU output row t
    const int lane = t & 63;
    const int wid  = t >> 6;             // 0..5
    const int b    = blockIdx.x;         // batch row 0..511

    __shared__ alignas(16) float sWlift[64 * 9];
    __shared__ float sblift[64];
    __shared__ alignas(16) float sWheadP[13 * 132];   // padded stride 132
    __shared__ float sbhead[16];
    __shared__ float sU2Y[20];                        // u2y row-major (U,P)
    __shared__ alignas(16) _Float16 sX2hi[64];        // x high f16
    __shared__ alignas(16) _Float16 sX2lo[64];        // x residual f16
    __shared__ alignas(16) h2v sWihLo[384 * 33];      // W_ih f16 residuals, 33-h2v stride
                                                      // (33 words ≡ 1 mod 32 banks: conflict-free)
    __shared__ alignas(16) float sH[128];             // h fp32 (head consumer)
    __shared__ alignas(16) _Float16 sH2[128];         // h f16 (gh consumer)
    __shared__ alignas(16) float sGi[384];            // full gi (pre-summed halves)
    __shared__ alignas(16) float sGh[384];
    __shared__ float sY[8];

    // ---- full-row f16-packed hi weights: 96 VGPRs, pinned ----
    h2v wih2[32];   // W_ih[t][0..63] (hi)
    h2v whh2[64];   // W_hh[t][0..127] (hi)
    {
        const float* p = W_ih + (size_t)t * 64;
#pragma unroll
        for (int i = 0; i < 32; i++)
            wih2[i] = h2v{(_Float16)p[2 * i], (_Float16)p[2 * i + 1]};
        const float* q = W_hh + (size_t)t * 128;
#pragma unroll
        for (int i = 0; i < 64; i++)
            whh2[i] = h2v{(_Float16)q[2 * i], (_Float16)q[2 * i + 1]};
    }
    const float bihv = b_ih[t];
    const float bhhv = b_hh[t];
#pragma unroll
    for (int i = 0; i < 32; i++) asm volatile("" : "+v"(wih2[i]));
#pragma unroll
    for (int i = 0; i < 64; i++) asm volatile("" : "+v"(whh2[i]));

    // ---- cooperative LDS init ----
    for (int i = t; i < 576; i += 384) sWlift[i] = W_lift[i];
    if (t < 64) sblift[t] = b_lift[t];
    for (int i = t; i < 13 * 128; i += 384) {
        int oo = i >> 7, c = i & 127;
        sWheadP[oo * 132 + c] = W_head[i];
    }
    for (int i = t; i < 384 * 32; i += 384) {   // W_ih residual pairs
        int oo = i >> 5, c = i & 31;
        float w0 = W_ih[(size_t)oo * 64 + 2 * c];
        float w1 = W_ih[(size_t)oo * 64 + 2 * c + 1];
        _Float16 h0 = (_Float16)w0, h1 = (_Float16)w1;
        sWihLo[oo * 33 + c] = h2v{(_Float16)(w0 - (float)h0), (_Float16)(w1 - (float)h1)};
    }
    if (t < 13) sbhead[t] = b_head[t];
    if (t < 20) sU2Y[t] = u2y[t];
    if (t < 128) {
        sH[t] = 0.0f;
        sH2[t] = (_Float16)0.0f;
    }
    if (t < 5) sY[t] = y0[b * 5 + t] + 0.01f;
    sGh[t] = bhhv;   // gh(0) = b_hh (h0 = 0)
    __syncthreads();

    // gi = (bih + Σ_half0 [hi,lo,wlo]) + (Σ_half1 ...) — exact v11 order
    auto do_gi = [&]() {
        float ga = bihv, gb = 0.0f;
        const h2v* xh = (const h2v*)&sX2hi[0];
        const h2v* xl = (const h2v*)&sX2lo[0];
        const h2v* wlo = &sWihLo[t * 33];
#pragma unroll
        for (int i = 0; i < 16; i++) {
            ga = fdot2(wih2[i], xh[i], ga);
            ga = fdot2(wih2[i], xl[i], ga);
            ga = fdot2(wlo[i], xh[i], ga);
        }
#pragma unroll
        for (int i = 16; i < 32; i++) {
            gb = fdot2(wih2[i], xh[i], gb);
            gb = fdot2(wih2[i], xl[i], gb);
            gb = fdot2(wlo[i], xh[i], gb);
        }
        sGi[t] = ga + gb;
    };
    // gh = (bhh + Σ_half0) + (Σ_half1) — exact v11 order
    auto do_gh = [&]() {
        float ga = bhhv, gb = 0.0f;
        const h2v* hp = (const h2v*)&sH2[0];
#pragma unroll
        for (int i = 0; i < 32; i++) ga = fdot2(whh2[i], hp[i], ga);
#pragma unroll
        for (int i = 32; i < 64; i++) gb = fdot2(whh2[i], hp[i], gb);
        sGh[t] = ga + gb;
    };
    auto do_lift = [&](float4 u0) {   // wave 0; lane = x-output index
        const float* wl = &sWlift[lane * 9];
        float a0 = sblift[lane];
        a0 = fmaf(wl[0], u0.x, a0);
        a0 = fmaf(wl[1], u0.y, a0);
        a0 = fmaf(wl[2], u0.z, a0);
        a0 = fmaf(wl[3], u0.w, a0);
        a0 = fmaf(wl[4], sY[0], a0);
        a0 = fmaf(wl[5], sY[1], a0);
        a0 = fmaf(wl[6], sY[2], a0);
        a0 = fmaf(wl[7], sY[3], a0);
        a0 = fmaf(wl[8], sY[4], a0);
        float x0 = a0 * sigf(a0);                 // silu fp32
        _Float16 xh = (_Float16)x0;
        sX2hi[lane] = xh;
        sX2lo[lane] = (_Float16)(x0 - (float)xh);
    };

    // ---- prologue: lift(0), gi(0) ----
    if (wid == 0) {
        float4 u0 = *(const float4*)&u_seq[((size_t)b * KST) * 4];
        do_lift(u0);
    }
    __syncthreads();
    do_gi();
    __syncthreads();

    for (int k = 0; k < KST; k++) {
        // ---------- Ψ1: gates(k) ----------
        if (t < 128) {
            int q = t;
            float ir  = sGi[q];
            float iz  = sGi[q + 128];
            float in_ = sGi[q + 256];
            float hr  = sGh[q];
            float hz  = sGh[q + 128];
            float hn  = sGh[q + 256];
            float rr = sigf(ir + hr);
            float z  = sigf(iz + hz);
            float n  = tanhfast(fmaf(rr, hn, in_));
            float h  = sH[q];
            float hnew = fmaf(z, h - n, n);
            sH[q] = hnew;
            sH2[q] = (_Float16)hnew;
        }
        __syncthreads();

        // ---------- Ψ2: gh(k+1) all waves; wave 0 also head -> RK4 -> lift ----------
        float4 ukr{}, un{};
        float dtr = 0.0f;
        if (wid == 0) {   // early global loads (L2-resident); latency hides under gh
            int kn = (k + 1 < KST) ? k + 1 : KST - 1;
            ukr = *(const float4*)&u_seq[((size_t)b * KST + k) * 4];
            dtr = dt_seq[(size_t)b * KST + k];
            un  = *(const float4*)&u_seq[((size_t)b * KST + kn) * 4];
        }
        do_gh();
        if (wid == 0) {
            // ----- head: lane = hh*32 + oo; exact v11 summation tree -----
            const int hh = lane >> 5;
            const int oo = lane & 31;
            float accv[4] = {0.f, 0.f, 0.f, 0.f};
            if (oo < 13) {
                const float4* wv = (const float4*)&sWheadP[oo * 132 + hh * 64];
                const float4* hv = (const float4*)&sH[hh * 64];
#pragma unroll
                for (int c = 0; c < 4; c++) {
                    float4 w0 = wv[4 * c], w1 = wv[4 * c + 1], w2 = wv[4 * c + 2], w3 = wv[4 * c + 3];
                    float4 h0 = hv[4 * c], h1 = hv[4 * c + 1], h2 = hv[4 * c + 2], h3 = hv[4 * c + 3];
                    float a0 = w0.x * h0.x, a1 = w2.x * h2.x;
                    a0 = fmaf(w0.y, h0.y, a0); a1 = fmaf(w2.y, h2.y, a1);
                    a0 = fmaf(w0.z, h0.z, a0); a1 = fmaf(w2.z, h2.z, a1);
                    a0 = fmaf(w0.w, h0.w, a0); a1 = fmaf(w2.w, h2.w, a1);
                    a0 = fmaf(w1.x, h1.x, a0); a1 = fmaf(w3.x, h3.x, a1);
                    a0 = fmaf(w1.y, h1.y, a0); a1 = fmaf(w3.y, h3.y, a1);
                    a0 = fmaf(w1.z, h1.z, a0); a1 = fmaf(w3.z, h3.z, a1);
                    a0 = fmaf(w1.w, h1.w, a0); a1 = fmaf(w3.w, h3.w, a1);
                    accv[c] = a0 + a1;
                }
            }
            float p1 = accv[0] + accv[1];
            float p2 = accv[2] + accv[3];
            float part = p1 + p2;
            float tot = part + __shfl_xor(part, 32);   // hh halves combine
            float gval = 0.0f;
            if (oo < 13 && hh == 0) {
                float raw = tot + sbhead[oo];
                if (oo < 8) {
                    gval = fmaf(2.99f, sigf(raw), 0.01f);
                    out[OFF_R + ((size_t)b * KST + k) * 8 + oo] = gval;
                } else {
                    gval = 3.0f * sigf(raw);
                    out[OFF_D + ((size_t)b * KST + k) * 5 + (oo - 8)] = gval;
                }
            }

            // ----- RK4, state-per-lane (exact v11 expressions, single row) -----
            const int i = lane & 15;
            float kf = __shfl(gval, i - 1);
            float kr = __shfl(gval, i + 3);
            if (!(i >= 1 && i <= 4)) { kf = 0.0f; kr = 0.0f; }
            float dh = __shfl(gval, 8 + i);
            const int ii = (i < 5) ? i : 0;
            float yp = sY[ii];
            float jmp = ukr.x * sU2Y[ii];
            jmp = fmaf(ukr.y, sU2Y[5 + ii], jmp);
            jmp = fmaf(ukr.z, sU2Y[10 + ii], jmp);
            jmp = fmaf(ukr.w, sU2Y[15 + ii], jmp);
            float ya = yp + jmp + dh;
            const float hs = dtr * 0.1f;
            const float h2s = 0.5f * hs;
            const float h6 = hs * (1.0f / 6.0f);
#pragma unroll
            for (int ss = 0; ss < 10; ss++) {
                float yv = dpp_shr1(ya);
                float f1 = kf * yv - kr * ya;
                float k1 = f1 - dpp_shl1(f1);
                float tp = fmaf(h2s, k1, ya);
                yv = dpp_shr1(tp);
                float f2 = kf * yv - kr * tp;
                float k2 = f2 - dpp_shl1(f2);
                tp = fmaf(h2s, k2, ya);
                yv = dpp_shr1(tp);
                float f3 = kf * yv - kr * tp;
                float k3 = f3 - dpp_shl1(f3);
                tp = fmaf(hs, k3, ya);
                yv = dpp_shr1(tp);
                float f4 = kf * yv - kr * tp;
                float k4 = f4 - dpp_shl1(f4);
                float sum = k1 + 2.0f * (k2 + k3) + k4;
                ya = fmaxf(fmaf(h6, sum, ya), 0.0f);
            }
            if (lane < 5) {
                sY[lane] = ya;
                out[((size_t)b * KST + k) * 5 + lane] = ya;
            }
            asm volatile("s_waitcnt lgkmcnt(0)" ::: "memory");   // sY visible wave-wide
            do_lift(un);                                         // lift(k+1)
        }
        __syncthreads();

        // ---------- Ψ3: gi(k+1) ----------
        do_gi();
        __syncthreads();
    }
}

}  // namespace

extern "C" void kernel_launch(void* const* d_in, const int* in_sizes, int n_in,
                              void* d_out, int out_size, void* d_ws, size_t ws_size,
                              hipStream_t stream) {
    const float* y0     = (const float*)d_in[0];
    const float* u_seq  = (const float*)d_in[1];
    const float* dt_seq = (const float*)d_in[2];
    const float* W_lift = (const float*)d_in[3];
    const float* b_lift = (const float*)d_in[4];
    const float* W_ih   = (const float*)d_in[5];
    const float* W_hh   = (const float*)d_in[6];
    const float* b_ih   = (const float*)d_in[7];
    const float* b_hh   = (const float*)d_in[8];
    const float* W_head = (const float*)d_in[9];
    const float* b_head = (const float*)d_in[10];
    const float* u2y    = (const float*)d_in[11];
    float* out = (float*)d_out;

    rnn_v13<<<512, 384, 0, stream>>>(y0, u_seq, dt_seq, W_lift, b_lift,
                                     W_ih, W_hh, b_ih, b_hh, W_head, b_head,
                                     u2y, out);
}

// Round 14
// 5226.554 us; speedup vs baseline: 1.0608x; 1.0608x over previous
//
#include <hip/hip_runtime.h>

namespace {

typedef _Float16 __attribute__((ext_vector_type(2))) h2v;   // one VGPR = 2 f16

constexpr int KST = 1024;
constexpr size_t OFF_R = (size_t)512 * KST * 5;
constexpr size_t OFF_D = OFF_R + (size_t)512 * KST * 8;

__device__ __forceinline__ float sigf(float x) { return 1.0f / (1.0f + __expf(-x)); }
__device__ __forceinline__ float tanhfast(float x) {
    float e2 = __expf(2.0f * x);
    return 1.0f - 2.0f / (e2 + 1.0f);
}
__device__ __forceinline__ float fdot2(h2v a, h2v b, float c) {
    return __builtin_amdgcn_fdot2(a, b, c, false);
}
// DPP lane shifts within 16-lane rows (0-fill at edges) — state-per-lane RK4.
__device__ __forceinline__ float dpp_shr1(float v) {   // lane i <- lane i-1
    return __builtin_bit_cast(float, __builtin_amdgcn_update_dpp(
        0, __builtin_bit_cast(int, v), 0x111, 0xf, 0xf, true));
}
__device__ __forceinline__ float dpp_shl1(float v) {   // lane i <- lane i+1
    return __builtin_bit_cast(float, __builtin_amdgcn_update_dpp(
        0, __builtin_bit_cast(int, v), 0x101, 0xf, 0xf, true));
}

// v14 = v13 with W_ih residuals moved LDS -> REGISTERS (scaled by 2^12 so the
// tiny residuals sit in f16 NORMAL range — raw residuals ~3e-5 were subnormal
// in the LDS version; this is strictly more accurate). Separate lo-accumulator,
// one exact *0x1p-12f at the end. Pinned regs: 96 hi + 16 lo = 112 <= 128
// budget (law: 384-thread WG -> 128). LDS collapses 64.5 KB -> ~14 KB, so
// 2 WGs/CU co-reside (v13's blocker): 12 waves/CU in two INDEPENDENT barrier
// groups — one WG's LDS-latency / serial-tail stalls are filled by the other.
__global__ __launch_bounds__(384, 2) void rnn_v14(
    const float* __restrict__ y0,     const float* __restrict__ u_seq,
    const float* __restrict__ dt_seq, const float* __restrict__ W_lift,
    const float* __restrict__ b_lift, const float* __restrict__ W_ih,
    const float* __restrict__ W_hh,   const float* __restrict__ b_ih,
    const float* __restrict__ b_hh,   const float* __restrict__ W_head,
    const float* __restrict__ b_head, const float* __restrict__ u2y,
    float* __restrict__ out)
{
    const int t    = threadIdx.x;        // 0..383 ; owns GRU output row t
    const int lane = t & 63;
    const int wid  = t >> 6;             // 0..5
    const int b    = blockIdx.x;         // batch row 0..511

    __shared__ alignas(16) float sWlift[64 * 9];
    __shared__ float sblift[64];
    __shared__ alignas(16) float sWheadP[13 * 132];   // padded stride 132
    __shared__ float sbhead[16];
    __shared__ float sU2Y[20];                        // u2y row-major (U,P)
    __shared__ alignas(16) _Float16 sX2hi[64];        // x high f16
    __shared__ alignas(16) _Float16 sX2lo[64];        // x residual f16
    __shared__ alignas(16) float sH[128];             // h fp32 (head consumer)
    __shared__ alignas(16) _Float16 sH2[128];         // h f16 (gh consumer)
    __shared__ alignas(16) float sGi[384];            // full gi
    __shared__ alignas(16) float sGh[384];
    __shared__ float sY[8];

    // ---- full-row weights in regs: 96 hi + 16 scaled-lo = 112 VGPRs, pinned ----
    h2v wih2[32];   // W_ih[t][0..63] hi
    h2v wlo2[16];   // W_ih[t][0..31] residuals * 2^12  (second half below)
    h2v wlo2b[16];  // W_ih[t][32..63] residuals * 2^12
    h2v whh2[64];   // W_hh[t][0..127] hi
    {
        const float* p = W_ih + (size_t)t * 64;
#pragma unroll
        for (int i = 0; i < 32; i++) {
            float w0 = p[2 * i], w1 = p[2 * i + 1];
            _Float16 h0 = (_Float16)w0, h1 = (_Float16)w1;
            wih2[i] = h2v{h0, h1};
            h2v lo = h2v{(_Float16)((w0 - (float)h0) * 4096.0f),
                         (_Float16)((w1 - (float)h1) * 4096.0f)};
            if (i < 16) wlo2[i] = lo; else wlo2b[i - 16] = lo;
        }
        const float* q = W_hh + (size_t)t * 128;
#pragma unroll
        for (int i = 0; i < 64; i++)
            whh2[i] = h2v{(_Float16)q[2 * i], (_Float16)q[2 * i + 1]};
    }
    const float bihv = b_ih[t];
    const float bhhv = b_hh[t];
#pragma unroll
    for (int i = 0; i < 32; i++) asm volatile("" : "+v"(wih2[i]));
#pragma unroll
    for (int i = 0; i < 16; i++) asm volatile("" : "+v"(wlo2[i]));
#pragma unroll
    for (int i = 0; i < 16; i++) asm volatile("" : "+v"(wlo2b[i]));
#pragma unroll
    for (int i = 0; i < 64; i++) asm volatile("" : "+v"(whh2[i]));

    // ---- cooperative LDS init ----
    for (int i = t; i < 576; i += 384) sWlift[i] = W_lift[i];
    if (t < 64) sblift[t] = b_lift[t];
    for (int i = t; i < 13 * 128; i += 384) {
        int oo = i >> 7, c = i & 127;
        sWheadP[oo * 132 + c] = W_head[i];
    }
    if (t < 13) sbhead[t] = b_head[t];
    if (t < 20) sU2Y[t] = u2y[t];
    if (t < 128) {
        sH[t] = 0.0f;
        sH2[t] = (_Float16)0.0f;
    }
    if (t < 5) sY[t] = y0[b * 5 + t] + 0.01f;
    sGh[t] = bhhv;   // gh(0) = b_hh (h0 = 0)
    __syncthreads();

    // gi = [(bih + hi/lo terms half0) + (half1)] + 2^-12 * [lo-residual terms]
    auto do_gi = [&]() {
        float ga = bihv, gb = 0.0f, gl0 = 0.0f, gl1 = 0.0f;
        const h2v* xh = (const h2v*)&sX2hi[0];
        const h2v* xl = (const h2v*)&sX2lo[0];
#pragma unroll
        for (int i = 0; i < 16; i++) {
            ga  = fdot2(wih2[i], xh[i], ga);
            ga  = fdot2(wih2[i], xl[i], ga);
            gl0 = fdot2(wlo2[i], xh[i], gl0);
        }
#pragma unroll
        for (int i = 16; i < 32; i++) {
            gb  = fdot2(wih2[i], xh[i], gb);
            gb  = fdot2(wih2[i], xl[i], gb);
            gl1 = fdot2(wlo2b[i - 16], xh[i], gl1);
        }
        sGi[t] = (ga + gb) + (gl0 + gl1) * 0x1p-12f;
    };
    auto do_gh = [&]() {
        float ga = bhhv, gb = 0.0f;
        const h2v* hp = (const h2v*)&sH2[0];
#pragma unroll
        for (int i = 0; i < 32; i++) ga = fdot2(whh2[i], hp[i], ga);
#pragma unroll
        for (int i = 32; i < 64; i++) gb = fdot2(whh2[i], hp[i], gb);
        sGh[t] = ga + gb;
    };
    auto do_lift = [&](float4 u0) {   // wave 0; lane = x-output index
        const float* wl = &sWlift[lane * 9];
        float a0 = sblift[lane];
        a0 = fmaf(wl[0], u0.x, a0);
        a0 = fmaf(wl[1], u0.y, a0);
        a0 = fmaf(wl[2], u0.z, a0);
        a0 = fmaf(wl[3], u0.w, a0);
        a0 = fmaf(wl[4], sY[0], a0);
        a0 = fmaf(wl[5], sY[1], a0);
        a0 = fmaf(wl[6], sY[2], a0);
        a0 = fmaf(wl[7], sY[3], a0);
        a0 = fmaf(wl[8], sY[4], a0);
        float x0 = a0 * sigf(a0);                 // silu fp32
        _Float16 xh = (_Float16)x0;
        sX2hi[lane] = xh;
        sX2lo[lane] = (_Float16)(x0 - (float)xh);
    };

    // ---- prologue: lift(0), gi(0) ----
    if (wid == 0) {
        float4 u0 = *(const float4*)&u_seq[((size_t)b * KST) * 4];
        do_lift(u0);
    }
    __syncthreads();
    do_gi();
    __syncthreads();

    for (int k = 0; k < KST; k++) {
        // ---------- Ψ1: gates(k) ----------
        if (t < 128) {
            int q = t;
            float ir  = sGi[q];
            float iz  = sGi[q + 128];
            float in_ = sGi[q + 256];
            float hr  = sGh[q];
            float hz  = sGh[q + 128];
            float hn  = sGh[q + 256];
            float rr = sigf(ir + hr);
            float z  = sigf(iz + hz);
            float n  = tanhfast(fmaf(rr, hn, in_));
            float h  = sH[q];
            float hnew = fmaf(z, h - n, n);
            sH[q] = hnew;
            sH2[q] = (_Float16)hnew;
        }
        __syncthreads();

        // ---------- Ψ2: gh(k+1) all waves; wave 0 also head -> RK4 -> lift ----------
        float4 ukr{}, un{};
        float dtr = 0.0f;
        if (wid == 0) {   // early global loads (L2-resident); latency hides under gh
            int kn = (k + 1 < KST) ? k + 1 : KST - 1;
            ukr = *(const float4*)&u_seq[((size_t)b * KST + k) * 4];
            dtr = dt_seq[(size_t)b * KST + k];
            un  = *(const float4*)&u_seq[((size_t)b * KST + kn) * 4];
        }
        do_gh();
        if (wid == 0) {
            // ----- head: lane = hh*32 + oo; exact v13 summation tree -----
            const int hh = lane >> 5;
            const int oo = lane & 31;
            float accv[4] = {0.f, 0.f, 0.f, 0.f};
            if (oo < 13) {
                const float4* wv = (const float4*)&sWheadP[oo * 132 + hh * 64];
                const float4* hv = (const float4*)&sH[hh * 64];
#pragma unroll
                for (int c = 0; c < 4; c++) {
                    float4 w0 = wv[4 * c], w1 = wv[4 * c + 1], w2 = wv[4 * c + 2], w3 = wv[4 * c + 3];
                    float4 h0 = hv[4 * c], h1 = hv[4 * c + 1], h2 = hv[4 * c + 2], h3 = hv[4 * c + 3];
                    float a0 = w0.x * h0.x, a1 = w2.x * h2.x;
                    a0 = fmaf(w0.y, h0.y, a0); a1 = fmaf(w2.y, h2.y, a1);
                    a0 = fmaf(w0.z, h0.z, a0); a1 = fmaf(w2.z, h2.z, a1);
                    a0 = fmaf(w0.w, h0.w, a0); a1 = fmaf(w2.w, h2.w, a1);
                    a0 = fmaf(w1.x, h1.x, a0); a1 = fmaf(w3.x, h3.x, a1);
                    a0 = fmaf(w1.y, h1.y, a0); a1 = fmaf(w3.y, h3.y, a1);
                    a0 = fmaf(w1.z, h1.z, a0); a1 = fmaf(w3.z, h3.z, a1);
                    a0 = fmaf(w1.w, h1.w, a0); a1 = fmaf(w3.w, h3.w, a1);
                    accv[c] = a0 + a1;
                }
            }
            float p1 = accv[0] + accv[1];
            float p2 = accv[2] + accv[3];
            float part = p1 + p2;
            float tot = part + __shfl_xor(part, 32);   // hh halves combine
            float gval = 0.0f;
            if (oo < 13 && hh == 0) {
                float raw = tot + sbhead[oo];
                if (oo < 8) {
                    gval = fmaf(2.99f, sigf(raw), 0.01f);
                    out[OFF_R + ((size_t)b * KST + k) * 8 + oo] = gval;
                } else {
                    gval = 3.0f * sigf(raw);
                    out[OFF_D + ((size_t)b * KST + k) * 5 + (oo - 8)] = gval;
                }
            }

            // ----- RK4, state-per-lane (exact v13 expressions) -----
            const int i = lane & 15;
            float kf = __shfl(gval, i - 1);
            float kr = __shfl(gval, i + 3);
            if (!(i >= 1 && i <= 4)) { kf = 0.0f; kr = 0.0f; }
            float dh = __shfl(gval, 8 + i);
            const int ii = (i < 5) ? i : 0;
            float yp = sY[ii];
            float jmp = ukr.x * sU2Y[ii];
            jmp = fmaf(ukr.y, sU2Y[5 + ii], jmp);
            jmp = fmaf(ukr.z, sU2Y[10 + ii], jmp);
            jmp = fmaf(ukr.w, sU2Y[15 + ii], jmp);
            float ya = yp + jmp + dh;
            const float hs = dtr * 0.1f;
            const float h2s = 0.5f * hs;
            const float h6 = hs * (1.0f / 6.0f);
#pragma unroll
            for (int ss = 0; ss < 10; ss++) {
                float yv = dpp_shr1(ya);
                float f1 = kf * yv - kr * ya;
                float k1 = f1 - dpp_shl1(f1);
                float tp = fmaf(h2s, k1, ya);
                yv = dpp_shr1(tp);
                float f2 = kf * yv - kr * tp;
                float k2 = f2 - dpp_shl1(f2);
                tp = fmaf(h2s, k2, ya);
                yv = dpp_shr1(tp);
                float f3 = kf * yv - kr * tp;
                float k3 = f3 - dpp_shl1(f3);
                tp = fmaf(hs, k3, ya);
                yv = dpp_shr1(tp);
                float f4 = kf * yv - kr * tp;
                float k4 = f4 - dpp_shl1(f4);
                float sum = k1 + 2.0f * (k2 + k3) + k4;
                ya = fmaxf(fmaf(h6, sum, ya), 0.0f);
            }
            if (lane < 5) {
                sY[lane] = ya;
                out[((size_t)b * KST + k) * 5 + lane] = ya;
            }
            asm volatile("s_waitcnt lgkmcnt(0)" ::: "memory");   // sY visible wave-wide
            do_lift(un);                                         // lift(k+1)
        }
        __syncthreads();

        // ---------- Ψ3: gi(k+1) ----------
        do_gi();
        __syncthreads();
    }
}

}  // namespace

extern "C" void kernel_launch(void* const* d_in, const int* in_sizes, int n_in,
                              void* d_out, int out_size, void* d_ws, size_t ws_size,
                              hipStream_t stream) {
    const float* y0     = (const float*)d_in[0];
    const float* u_seq  = (const float*)d_in[1];
    const float* dt_seq = (const float*)d_in[2];
    const float* W_lift = (const float*)d_in[3];
    const float* b_lift = (const float*)d_in[4];
    const float* W_ih   = (const float*)d_in[5];
    const float* W_hh   = (const float*)d_in[6];
    const float* b_ih   = (const float*)d_in[7];
    const float* b_hh   = (const float*)d_in[8];
    const float* W_head = (const float*)d_in[9];
    const float* b_head = (const float*)d_in[10];
    const float* u2y    = (const float*)d_in[11];
    float* out = (float*)d_out;

    rnn_v14<<<512, 384, 0, stream>>>(y0, u_seq, dt_seq, W_lift, b_lift,
                                     W_ih, W_hh, b_ih, b_hh, W_head, b_head,
                                     u2y, out);
}

// Round 15
// 3167.410 us; speedup vs baseline: 1.7504x; 1.6501x over previous
//
#include <hip/hip_runtime.h>

namespace {

typedef _Float16 __attribute__((ext_vector_type(2))) h2v;   // one VGPR = 2 f16

constexpr int KST = 1024;
constexpr size_t OFF_R = (size_t)512 * KST * 5;
constexpr size_t OFF_D = OFF_R + (size_t)512 * KST * 8;

__device__ __forceinline__ float sigf(float x) { return 1.0f / (1.0f + __expf(-x)); }
__device__ __forceinline__ float tanhfast(float x) {
    float e2 = __expf(2.0f * x);
    return 1.0f - 2.0f / (e2 + 1.0f);
}
__device__ __forceinline__ float fdot2(h2v a, h2v b, float c) {
    return __builtin_amdgcn_fdot2(a, b, c, false);
}
// DPP lane shifts within 16-lane rows (0-fill at edges) — state-per-lane RK4.
__device__ __forceinline__ float dpp_shr1(float v) {   // lane i <- lane i-1
    return __builtin_bit_cast(float, __builtin_amdgcn_update_dpp(
        0, __builtin_bit_cast(int, v), 0x111, 0xf, 0xf, true));
}
__device__ __forceinline__ float dpp_shl1(float v) {   // lane i <- lane i+1
    return __builtin_bit_cast(float, __builtin_amdgcn_update_dpp(
        0, __builtin_bit_cast(int, v), 0x101, 0xf, 0xf, true));
}

// v15 = v11 (best: 3178us) + two wave-0 tail latency cuts:
//  (1) y lives in wave-0 REGISTERS across steps (state-per-lane); do_lift gets
//      it via __shfl broadcast — removes the sY write->lgkmcnt->read round trip
//      from the serial tail. Bit-identical values.
//  (2) RK4 stage uses the tridiagonal 3-term form k_i = kf_i*y[i-1]
//      - (kr_i+kf_{i+1})*y[i] + kr_{i+1}*y[i+1] with per-lane constants:
//      one dependent DPP per stage instead of two (24->16 cyc), regrouping
//      perturbs ~1e-7 rel — 5 orders under the ~0.02 gate-error flip threshold.
// Occupancy law (r13/r14 evidence): schedulable arch-VGPR pool = 256/SIMD;
// v11's 84-reg / 12-wave config is AT the cap — co-residency is unreachable.
__global__ __launch_bounds__(768, 3) void rnn_v15(
    const float* __restrict__ y0,     const float* __restrict__ u_seq,
    const float* __restrict__ dt_seq, const float* __restrict__ W_lift,
    const float* __restrict__ b_lift, const float* __restrict__ W_ih,
    const float* __restrict__ W_hh,   const float* __restrict__ b_ih,
    const float* __restrict__ b_hh,   const float* __restrict__ W_head,
    const float* __restrict__ b_head, const float* __restrict__ u2y,
    float* __restrict__ out)
{
    const int t    = threadIdx.x;        // 0..767
    const int lane = t & 63;
    const int wid  = t >> 6;
    const int hf   = (t >= 384) ? 1 : 0; // column half (wave-uniform)
    const int o    = t - hf * 384;       // owned GRU output row 0..383
    const int b0   = blockIdx.x * 2;     // two batch rows per WG
    const int rh   = (lane >> 4) & 1;    // RK4 row for this lane
    const int ri   = lane & 15;          // RK4 state index (junk >4)

    __shared__ alignas(16) float sWlift[64 * 9];
    __shared__ float sblift[64];
    __shared__ alignas(16) float sWheadP[13 * 132];      // padded stride 132
    __shared__ float sbhead[16];
    __shared__ float sU2Y[20];                           // u2y row-major (U,P)
    __shared__ alignas(16) _Float16 sX2hi[2][64];        // x high f16
    __shared__ alignas(16) _Float16 sX2lo[2][64];        // x residual f16
    __shared__ alignas(16) _Float16 sWihLo[2][384][36];  // W_ih f16 residuals (72B stride)
    __shared__ alignas(16) float sH[2][128];             // h fp32 (head consumer)
    __shared__ alignas(16) _Float16 sH2[2][128];         // h f16 (gh consumer)
    __shared__ alignas(16) float sGiP[2][2][384];        // [half][row][out]
    __shared__ alignas(16) float sGhP[2][2][384];

    // ---- f16-packed per-thread hi weight rows (48 VGPRs) ----
    h2v wih2[16];   // W_ih[o][hf*32 .. +31] (hi)
    h2v whh2[32];   // W_hh[o][hf*64 .. +63] (hi)
    {
        const float* p = W_ih + (size_t)o * 64 + hf * 32;
#pragma unroll
        for (int i = 0; i < 16; i++)
            wih2[i] = h2v{(_Float16)p[2 * i], (_Float16)p[2 * i + 1]};
        const float* q = W_hh + (size_t)o * 128 + hf * 64;
#pragma unroll
        for (int i = 0; i < 32; i++)
            whh2[i] = h2v{(_Float16)q[2 * i], (_Float16)q[2 * i + 1]};
    }
    const float bihv = hf ? 0.0f : b_ih[o];
    const float bhhv = hf ? 0.0f : b_hh[o];
#pragma unroll
    for (int i = 0; i < 16; i++) asm volatile("" : "+v"(wih2[i]));
#pragma unroll
    for (int i = 0; i < 32; i++) asm volatile("" : "+v"(whh2[i]));

    // ---- cooperative LDS init ----
    for (int i = t; i < 576; i += 768) sWlift[i] = W_lift[i];
    if (t < 64) sblift[t] = b_lift[t];
    for (int i = t; i < 13 * 128; i += 768) {
        int oo = i >> 7, c = i & 127;
        sWheadP[oo * 132 + c] = W_head[i];
    }
    for (int i = t; i < 2 * 384 * 32; i += 768) {   // W_ih residuals
        int hh = i / (384 * 32);
        int rem = i - hh * 384 * 32;
        int oo = rem >> 5, c = rem & 31;
        float w = W_ih[(size_t)oo * 64 + hh * 32 + c];
        _Float16 wh = (_Float16)w;
        sWihLo[hh][oo][c] = (_Float16)(w - (float)wh);
    }
    if (t < 13) sbhead[t] = b_head[t];
    if (t < 20) sU2Y[t] = u2y[t];
    if (t < 256) {
        sH[t >> 7][t & 127] = 0.0f;
        sH2[t >> 7][t & 127] = (_Float16)0.0f;
    }
    sGhP[hf][0][o] = bhhv;   // gh(0) = b_hh (h0 = 0)
    sGhP[hf][1][o] = bhhv;

    // ---- wave-0 persistent y state (state-per-lane) ----
    float yreg = 0.0f;
    if (wid == 0)
        yreg = y0[(b0 + rh) * 5 + ((ri < 5) ? ri : 0)] + 0.01f;
    __syncthreads();

    auto do_gi = [&]() {   // gi = Whi*xhi + Whi*xlo + Wlo*xhi  (exact v11 order)
        float g0 = bihv, g1 = 0.0f;
        const h2v* xh0 = (const h2v*)&sX2hi[0][hf * 32];
        const h2v* xh1 = (const h2v*)&sX2hi[1][hf * 32];
        const h2v* xl0 = (const h2v*)&sX2lo[0][hf * 32];
        const h2v* xl1 = (const h2v*)&sX2lo[1][hf * 32];
        const h2v* wlo = (const h2v*)&sWihLo[hf][o][0];
#pragma unroll
        for (int i = 0; i < 16; i++) {
            h2v wl = wlo[i];
            g0 = fdot2(wih2[i], xh0[i], g0);
            g0 = fdot2(wih2[i], xl0[i], g0);
            g0 = fdot2(wl, xh0[i], g0);
            g1 = fdot2(wih2[i], xh1[i], g1);
            g1 = fdot2(wih2[i], xl1[i], g1);
            g1 = fdot2(wl, xh1[i], g1);
        }
        sGiP[hf][0][o] = g0;
        sGiP[hf][1][o] = g1;
    };
    auto do_gh = [&]() {
        float g0 = bhhv, g1 = 0.0f;
        const h2v* h0p = (const h2v*)&sH2[0][hf * 64];
        const h2v* h1p = (const h2v*)&sH2[1][hf * 64];
#pragma unroll
        for (int i = 0; i < 32; i++) {
            g0 = fdot2(whh2[i], h0p[i], g0);
            g1 = fdot2(whh2[i], h1p[i], g1);
        }
        sGhP[hf][0][o] = g0;
        sGhP[hf][1][o] = g1;
    };
    // wave 0; lane = x-output index; y delivered via in-wave shfl broadcast
    auto do_lift = [&](float4 u0, float4 u1, float yr) {
        float y00 = __shfl(yr, 0),  y01 = __shfl(yr, 1),  y02 = __shfl(yr, 2);
        float y03 = __shfl(yr, 3),  y04 = __shfl(yr, 4);
        float y10 = __shfl(yr, 16), y11 = __shfl(yr, 17), y12 = __shfl(yr, 18);
        float y13 = __shfl(yr, 19), y14 = __shfl(yr, 20);
        const float* wl = &sWlift[lane * 9];
        float bl = sblift[lane];
        float a0 = bl, a1 = bl;
        a0 = fmaf(wl[0], u0.x, a0);   a1 = fmaf(wl[0], u1.x, a1);
        a0 = fmaf(wl[1], u0.y, a0);   a1 = fmaf(wl[1], u1.y, a1);
        a0 = fmaf(wl[2], u0.z, a0);   a1 = fmaf(wl[2], u1.z, a1);
        a0 = fmaf(wl[3], u0.w, a0);   a1 = fmaf(wl[3], u1.w, a1);
        a0 = fmaf(wl[4], y00, a0);    a1 = fmaf(wl[4], y10, a1);
        a0 = fmaf(wl[5], y01, a0);    a1 = fmaf(wl[5], y11, a1);
        a0 = fmaf(wl[6], y02, a0);    a1 = fmaf(wl[6], y12, a1);
        a0 = fmaf(wl[7], y03, a0);    a1 = fmaf(wl[7], y13, a1);
        a0 = fmaf(wl[8], y04, a0);    a1 = fmaf(wl[8], y14, a1);
        float x0 = a0 * sigf(a0), x1 = a1 * sigf(a1);   // silu fp32
        _Float16 xh0 = (_Float16)x0;
        sX2hi[0][lane] = xh0;
        sX2lo[0][lane] = (_Float16)(x0 - (float)xh0);
        _Float16 xh1 = (_Float16)x1;
        sX2hi[1][lane] = xh1;
        sX2lo[1][lane] = (_Float16)(x1 - (float)xh1);
    };

    // ---- prologue: lift(0), gi(0) ----
    if (wid == 0) {
        float4 u0 = *(const float4*)&u_seq[((size_t)b0 * KST) * 4];
        float4 u1 = *(const float4*)&u_seq[((size_t)(b0 + 1) * KST) * 4];
        do_lift(u0, u1, yreg);
    }
    __syncthreads();
    do_gi();
    __syncthreads();

    for (int k = 0; k < KST; k++) {
        // ---------- Ψ1: gates(k) ----------
        if (t < 256) {
            int r = t >> 7, q = t & 127;
            float ir  = sGiP[0][r][q]       + sGiP[1][r][q];
            float iz  = sGiP[0][r][q + 128] + sGiP[1][r][q + 128];
            float in_ = sGiP[0][r][q + 256] + sGiP[1][r][q + 256];
            float hr  = sGhP[0][r][q]       + sGhP[1][r][q];
            float hz  = sGhP[0][r][q + 128] + sGhP[1][r][q + 128];
            float hn  = sGhP[0][r][q + 256] + sGhP[1][r][q + 256];
            float rr = sigf(ir + hr);
            float z  = sigf(iz + hz);
            float n  = tanhfast(fmaf(rr, hn, in_));
            float h  = sH[r][q];
            float hnew = fmaf(z, h - n, n);
            sH[r][q] = hnew;
            sH2[r][q] = (_Float16)hnew;
        }
        __syncthreads();

        // ---------- Ψ2: gh(k+1) all waves; wave 0 also head -> RK4 -> lift ----------
        float4 ukr{}, un0{}, un1{};
        float dtr = 0.0f;
        if (wid == 0) {   // early global loads (L2-resident); latency hides under gh
            int kn = (k + 1 < KST) ? k + 1 : KST - 1;
            ukr = *(const float4*)&u_seq[((size_t)(b0 + rh) * KST + k) * 4];
            dtr = dt_seq[(size_t)(b0 + rh) * KST + k];
            un0 = *(const float4*)&u_seq[((size_t)b0 * KST + kn) * 4];
            un1 = *(const float4*)&u_seq[((size_t)(b0 + 1) * KST + kn) * 4];
        }
        do_gh();
        if (wid == 0) {
            // ----- head: lane = hh*32 + rh*16 + oo; exact v11 summation tree -----
            const int hh = (lane >> 5) & 1;
            const int oo = lane & 15;
            float accv[4] = {0.f, 0.f, 0.f, 0.f};
            if (oo < 13) {
                const float4* wv = (const float4*)&sWheadP[oo * 132 + hh * 64];
                const float4* hv = (const float4*)&sH[rh][hh * 64];
#pragma unroll
                for (int c = 0; c < 4; c++) {
                    float4 w0 = wv[4 * c], w1 = wv[4 * c + 1], w2 = wv[4 * c + 2], w3 = wv[4 * c + 3];
                    float4 h0 = hv[4 * c], h1 = hv[4 * c + 1], h2 = hv[4 * c + 2], h3 = hv[4 * c + 3];
                    float a0 = w0.x * h0.x, a1 = w2.x * h2.x;
                    a0 = fmaf(w0.y, h0.y, a0); a1 = fmaf(w2.y, h2.y, a1);
                    a0 = fmaf(w0.z, h0.z, a0); a1 = fmaf(w2.z, h2.z, a1);
                    a0 = fmaf(w0.w, h0.w, a0); a1 = fmaf(w2.w, h2.w, a1);
                    a0 = fmaf(w1.x, h1.x, a0); a1 = fmaf(w3.x, h3.x, a1);
                    a0 = fmaf(w1.y, h1.y, a0); a1 = fmaf(w3.y, h3.y, a1);
                    a0 = fmaf(w1.z, h1.z, a0); a1 = fmaf(w3.z, h3.z, a1);
                    a0 = fmaf(w1.w, h1.w, a0); a1 = fmaf(w3.w, h3.w, a1);
                    accv[c] = a0 + a1;
                }
            }
            float p1 = accv[0] + accv[1];
            float p2 = accv[2] + accv[3];
            float part = p1 + p2;                       // ((s0+s1)+(s2+s3))
            float tot = part + __shfl_xor(part, 32);    // + ((s4+s5)+(s6+s7))
            float gval = 0.0f;
            if (oo < 13 && hh == 0) {
                float raw = tot + sbhead[oo];
                if (oo < 8) {
                    gval = fmaf(2.99f, sigf(raw), 0.01f);
                    out[OFF_R + ((size_t)(b0 + rh) * KST + k) * 8 + oo] = gval;
                } else {
                    gval = 3.0f * sigf(raw);
                    out[OFF_D + ((size_t)(b0 + rh) * KST + k) * 5 + (oo - 8)] = gval;
                }
            }

            // ----- RK4, state-per-lane, tridiagonal 3-term form -----
            const int i = ri;
            const int base = rh * 16;
            float kf_l = __shfl(gval, base + i - 1);   // kf_i
            float kri  = __shfl(gval, base + i + 3);   // kr_i
            float krn  = __shfl(gval, base + i + 4);   // kr_{i+1}
            float kfn  = __shfl(gval, base + i);       // kf_{i+1}
            if (!(i >= 1 && i <= 4)) { kf_l = 0.0f; kri = 0.0f; }
            if (i > 3)                { krn = 0.0f; kfn = 0.0f; }
            const float dneg = -(kri + kfn);           // -(kr_i + kf_{i+1})
            float dh = __shfl(gval, base + 8 + i);
            float jmp;
            {
                const int ii = (i < 5) ? i : 0;
                jmp = ukr.x * sU2Y[ii];
                jmp = fmaf(ukr.y, sU2Y[5 + ii], jmp);
                jmp = fmaf(ukr.z, sU2Y[10 + ii], jmp);
                jmp = fmaf(ukr.w, sU2Y[15 + ii], jmp);
            }
            float ya = yreg + jmp + dh;
            const float hs = dtr * 0.1f;
            const float h2s = 0.5f * hs;
            const float h6 = hs * (1.0f / 6.0f);
#pragma unroll
            for (int ss = 0; ss < 10; ss++) {
                float s1r = dpp_shr1(ya), s1l = dpp_shl1(ya);
                float k1 = fmaf(kf_l, s1r, fmaf(krn, s1l, dneg * ya));
                float tp = fmaf(h2s, k1, ya);
                float s2r = dpp_shr1(tp), s2l = dpp_shl1(tp);
                float k2 = fmaf(kf_l, s2r, fmaf(krn, s2l, dneg * tp));
                tp = fmaf(h2s, k2, ya);
                float s3r = dpp_shr1(tp), s3l = dpp_shl1(tp);
                float k3 = fmaf(kf_l, s3r, fmaf(krn, s3l, dneg * tp));
                tp = fmaf(hs, k3, ya);
                float s4r = dpp_shr1(tp), s4l = dpp_shl1(tp);
                float k4 = fmaf(kf_l, s4r, fmaf(krn, s4l, dneg * tp));
                float sum = k1 + 2.0f * (k2 + k3) + k4;
                ya = fmaxf(fmaf(h6, sum, ya), 0.0f);
            }
            yreg = ya;
            if (lane < 32 && i < 5)
                out[((size_t)(b0 + rh) * KST + k) * 5 + i] = ya;
            do_lift(un0, un1, yreg);                     // lift(k+1), y via shfl
        }
        __syncthreads();

        // ---------- Ψ3: gi(k+1) ----------
        do_gi();
        __syncthreads();
    }
}

}  // namespace

extern "C" void kernel_launch(void* const* d_in, const int* in_sizes, int n_in,
                              void* d_out, int out_size, void* d_ws, size_t ws_size,
                              hipStream_t stream) {
    const float* y0     = (const float*)d_in[0];
    const float* u_seq  = (const float*)d_in[1];
    const float* dt_seq = (const float*)d_in[2];
    const float* W_lift = (const float*)d_in[3];
    const float* b_lift = (const float*)d_in[4];
    const float* W_ih   = (const float*)d_in[5];
    const float* W_hh   = (const float*)d_in[6];
    const float* b_ih   = (const float*)d_in[7];
    const float* b_hh   = (const float*)d_in[8];
    const float* W_head = (const float*)d_in[9];
    const float* b_head = (const float*)d_in[10];
    const float* u2y    = (const float*)d_in[11];
    float* out = (float*)d_out;

    rnn_v15<<<256, 768, 0, stream>>>(y0, u_seq, dt_seq, W_lift, b_lift,
                                     W_ih, W_hh, b_ih, b_hh, W_head, b_head,
                                     u2y, out);
}

// Round 16
// 3149.214 us; speedup vs baseline: 1.7605x; 1.0058x over previous
//
#include <hip/hip_runtime.h>

namespace {

typedef _Float16 __attribute__((ext_vector_type(2))) h2v;   // one VGPR = 2 f16

constexpr int KST = 1024;
constexpr size_t OFF_R = (size_t)512 * KST * 5;
constexpr size_t OFF_D = OFF_R + (size_t)512 * KST * 8;

__device__ __forceinline__ float sigf(float x) { return 1.0f / (1.0f + __expf(-x)); }
__device__ __forceinline__ float tanhfast(float x) {
    float e2 = __expf(2.0f * x);
    return 1.0f - 2.0f / (e2 + 1.0f);
}
__device__ __forceinline__ float fdot2(h2v a, h2v b, float c) {
    return __builtin_amdgcn_fdot2(a, b, c, false);
}

// v16 = v15 (best: 3167us) with ONE change: the wave-0 RK4 10-substep DPP
// chain (~40 dependent stages) is replaced by the M^10 formulation proven
// numerically in v12 (absmax 32): M = I + hB + (hB)^2/2 + (hB)^3/6 + (hB)^4/24
// is EXACTLY one RK4 substep of the linear chain ODE; the per-substep clamp is
// a no-op (M >= 0 entrywise, diag >= 0.94, strictly positive state).
// M^10 = ((M^2)^2 * M)^2 on 25 lanes/row cuts the tail's serial latency
// ~700-960 -> ~500 cyc. v12's regression came from its BUNDLED changes
// (gh moved to Psi3 + LDS y_jump fences), not from M^10 — here the v15
// schedule is kept byte-identical and y stays in wave-0 registers.
__global__ __launch_bounds__(768, 3) void rnn_v16(
    const float* __restrict__ y0,     const float* __restrict__ u_seq,
    const float* __restrict__ dt_seq, const float* __restrict__ W_lift,
    const float* __restrict__ b_lift, const float* __restrict__ W_ih,
    const float* __restrict__ W_hh,   const float* __restrict__ b_ih,
    const float* __restrict__ b_hh,   const float* __restrict__ W_head,
    const float* __restrict__ b_head, const float* __restrict__ u2y,
    float* __restrict__ out)
{
    const int t    = threadIdx.x;        // 0..767
    const int lane = t & 63;
    const int wid  = t >> 6;
    const int hf   = (t >= 384) ? 1 : 0; // column half (wave-uniform)
    const int o    = t - hf * 384;       // owned GRU output row 0..383
    const int b0   = blockIdx.x * 2;     // two batch rows per WG
    const int rh   = (lane >> 4) & 1;    // head/RK4 home row for this lane
    const int ri   = lane & 15;          // home state index (junk >4)

    // M^10 lane constants (25 active lanes per batch row)
    const int mr = (lane >= 32) ? 1 : 0;   // batch row served
    const int me = lane - mr * 32;         // entry id (>=25 junk)
    const int mi = me / 5;                 // matrix row (junk >4)
    const int mj = me - mi * 5;            // matrix col 0..4
    const int rowBase = mr * 32 + mi * 5;
    const int colBase = mr * 32 + mj;
    const bool mAct = (me < 25);

    __shared__ alignas(16) float sWlift[64 * 9];
    __shared__ float sblift[64];
    __shared__ alignas(16) float sWheadP[13 * 132];      // padded stride 132
    __shared__ float sbhead[16];
    __shared__ float sU2Y[20];                           // u2y row-major (U,P)
    __shared__ alignas(16) _Float16 sX2hi[2][64];        // x high f16
    __shared__ alignas(16) _Float16 sX2lo[2][64];        // x residual f16
    __shared__ alignas(16) _Float16 sWihLo[2][384][36];  // W_ih f16 residuals (72B stride)
    __shared__ alignas(16) float sH[2][128];             // h fp32 (head consumer)
    __shared__ alignas(16) _Float16 sH2[2][128];         // h f16 (gh consumer)
    __shared__ alignas(16) float sGiP[2][2][384];        // [half][row][out]
    __shared__ alignas(16) float sGhP[2][2][384];

    // ---- f16-packed per-thread hi weight rows (48 VGPRs) ----
    h2v wih2[16];   // W_ih[o][hf*32 .. +31] (hi)
    h2v whh2[32];   // W_hh[o][hf*64 .. +63] (hi)
    {
        const float* p = W_ih + (size_t)o * 64 + hf * 32;
#pragma unroll
        for (int i = 0; i < 16; i++)
            wih2[i] = h2v{(_Float16)p[2 * i], (_Float16)p[2 * i + 1]};
        const float* q = W_hh + (size_t)o * 128 + hf * 64;
#pragma unroll
        for (int i = 0; i < 32; i++)
            whh2[i] = h2v{(_Float16)q[2 * i], (_Float16)q[2 * i + 1]};
    }
    const float bihv = hf ? 0.0f : b_ih[o];
    const float bhhv = hf ? 0.0f : b_hh[o];
#pragma unroll
    for (int i = 0; i < 16; i++) asm volatile("" : "+v"(wih2[i]));
#pragma unroll
    for (int i = 0; i < 32; i++) asm volatile("" : "+v"(whh2[i]));

    // ---- cooperative LDS init ----
    for (int i = t; i < 576; i += 768) sWlift[i] = W_lift[i];
    if (t < 64) sblift[t] = b_lift[t];
    for (int i = t; i < 13 * 128; i += 768) {
        int oo = i >> 7, c = i & 127;
        sWheadP[oo * 132 + c] = W_head[i];
    }
    for (int i = t; i < 2 * 384 * 32; i += 768) {   // W_ih residuals
        int hh = i / (384 * 32);
        int rem = i - hh * 384 * 32;
        int oo = rem >> 5, c = rem & 31;
        float w = W_ih[(size_t)oo * 64 + hh * 32 + c];
        _Float16 wh = (_Float16)w;
        sWihLo[hh][oo][c] = (_Float16)(w - (float)wh);
    }
    if (t < 13) sbhead[t] = b_head[t];
    if (t < 20) sU2Y[t] = u2y[t];
    if (t < 256) {
        sH[t >> 7][t & 127] = 0.0f;
        sH2[t >> 7][t & 127] = (_Float16)0.0f;
    }
    sGhP[hf][0][o] = bhhv;   // gh(0) = b_hh (h0 = 0)
    sGhP[hf][1][o] = bhhv;

    // ---- wave-0 persistent y state (home layout: lane rh*16+i, i<5) ----
    float yreg = 0.0f;
    if (wid == 0)
        yreg = y0[(b0 + rh) * 5 + ((ri < 5) ? ri : 0)] + 0.01f;
    __syncthreads();

    auto do_gi = [&]() {   // gi = Whi*xhi + Whi*xlo + Wlo*xhi  (exact v11 order)
        float g0 = bihv, g1 = 0.0f;
        const h2v* xh0 = (const h2v*)&sX2hi[0][hf * 32];
        const h2v* xh1 = (const h2v*)&sX2hi[1][hf * 32];
        const h2v* xl0 = (const h2v*)&sX2lo[0][hf * 32];
        const h2v* xl1 = (const h2v*)&sX2lo[1][hf * 32];
        const h2v* wlo = (const h2v*)&sWihLo[hf][o][0];
#pragma unroll
        for (int i = 0; i < 16; i++) {
            h2v wl = wlo[i];
            g0 = fdot2(wih2[i], xh0[i], g0);
            g0 = fdot2(wih2[i], xl0[i], g0);
            g0 = fdot2(wl, xh0[i], g0);
            g1 = fdot2(wih2[i], xh1[i], g1);
            g1 = fdot2(wih2[i], xl1[i], g1);
            g1 = fdot2(wl, xh1[i], g1);
        }
        sGiP[hf][0][o] = g0;
        sGiP[hf][1][o] = g1;
    };
    auto do_gh = [&]() {
        float g0 = bhhv, g1 = 0.0f;
        const h2v* h0p = (const h2v*)&sH2[0][hf * 64];
        const h2v* h1p = (const h2v*)&sH2[1][hf * 64];
#pragma unroll
        for (int i = 0; i < 32; i++) {
            g0 = fdot2(whh2[i], h0p[i], g0);
            g1 = fdot2(whh2[i], h1p[i], g1);
        }
        sGhP[hf][0][o] = g0;
        sGhP[hf][1][o] = g1;
    };
    // wave 0; lane = x-output index; y delivered via in-wave shfl broadcast
    auto do_lift = [&](float4 u0, float4 u1, float yr) {
        float y00 = __shfl(yr, 0),  y01 = __shfl(yr, 1),  y02 = __shfl(yr, 2);
        float y03 = __shfl(yr, 3),  y04 = __shfl(yr, 4);
        float y10 = __shfl(yr, 16), y11 = __shfl(yr, 17), y12 = __shfl(yr, 18);
        float y13 = __shfl(yr, 19), y14 = __shfl(yr, 20);
        const float* wl = &sWlift[lane * 9];
        float bl = sblift[lane];
        float a0 = bl, a1 = bl;
        a0 = fmaf(wl[0], u0.x, a0);   a1 = fmaf(wl[0], u1.x, a1);
        a0 = fmaf(wl[1], u0.y, a0);   a1 = fmaf(wl[1], u1.y, a1);
        a0 = fmaf(wl[2], u0.z, a0);   a1 = fmaf(wl[2], u1.z, a1);
        a0 = fmaf(wl[3], u0.w, a0);   a1 = fmaf(wl[3], u1.w, a1);
        a0 = fmaf(wl[4], y00, a0);    a1 = fmaf(wl[4], y10, a1);
        a0 = fmaf(wl[5], y01, a0);    a1 = fmaf(wl[5], y11, a1);
        a0 = fmaf(wl[6], y02, a0);    a1 = fmaf(wl[6], y12, a1);
        a0 = fmaf(wl[7], y03, a0);    a1 = fmaf(wl[7], y13, a1);
        a0 = fmaf(wl[8], y04, a0);    a1 = fmaf(wl[8], y14, a1);
        float x0 = a0 * sigf(a0), x1 = a1 * sigf(a1);   // silu fp32
        _Float16 xh0 = (_Float16)x0;
        sX2hi[0][lane] = xh0;
        sX2lo[0][lane] = (_Float16)(x0 - (float)xh0);
        _Float16 xh1 = (_Float16)x1;
        sX2hi[1][lane] = xh1;
        sX2lo[1][lane] = (_Float16)(x1 - (float)xh1);
    };

    // ---- prologue: lift(0), gi(0) ----
    if (wid == 0) {
        float4 u0 = *(const float4*)&u_seq[((size_t)b0 * KST) * 4];
        float4 u1 = *(const float4*)&u_seq[((size_t)(b0 + 1) * KST) * 4];
        do_lift(u0, u1, yreg);
    }
    __syncthreads();
    do_gi();
    __syncthreads();

    for (int k = 0; k < KST; k++) {
        // ---------- Ψ1: gates(k) ----------
        if (t < 256) {
            int r = t >> 7, q = t & 127;
            float ir  = sGiP[0][r][q]       + sGiP[1][r][q];
            float iz  = sGiP[0][r][q + 128] + sGiP[1][r][q + 128];
            float in_ = sGiP[0][r][q + 256] + sGiP[1][r][q + 256];
            float hr  = sGhP[0][r][q]       + sGhP[1][r][q];
            float hz  = sGhP[0][r][q + 128] + sGhP[1][r][q + 128];
            float hn  = sGhP[0][r][q + 256] + sGhP[1][r][q + 256];
            float rr = sigf(ir + hr);
            float z  = sigf(iz + hz);
            float n  = tanhfast(fmaf(rr, hn, in_));
            float h  = sH[r][q];
            float hnew = fmaf(z, h - n, n);
            sH[r][q] = hnew;
            sH2[r][q] = (_Float16)hnew;
        }
        __syncthreads();

        // ---------- Ψ2: gh(k+1) all waves; wave 0 also head -> M^10 -> lift ----------
        float4 ukr{}, un0{}, un1{};
        float dtr = 0.0f;
        if (wid == 0) {   // early global loads (L2-resident); latency hides under gh
            int kn = (k + 1 < KST) ? k + 1 : KST - 1;
            ukr = *(const float4*)&u_seq[((size_t)(b0 + rh) * KST + k) * 4];
            dtr = dt_seq[(size_t)(b0 + rh) * KST + k];
            un0 = *(const float4*)&u_seq[((size_t)b0 * KST + kn) * 4];
            un1 = *(const float4*)&u_seq[((size_t)(b0 + 1) * KST + kn) * 4];
        }
        do_gh();
        if (wid == 0) {
            // ----- head: lane = hh*32 + rh*16 + oo; exact v11 summation tree -----
            const int hh = (lane >> 5) & 1;
            const int oo = lane & 15;
            float accv[4] = {0.f, 0.f, 0.f, 0.f};
            if (oo < 13) {
                const float4* wv = (const float4*)&sWheadP[oo * 132 + hh * 64];
                const float4* hv = (const float4*)&sH[rh][hh * 64];
#pragma unroll
                for (int c = 0; c < 4; c++) {
                    float4 w0 = wv[4 * c], w1 = wv[4 * c + 1], w2 = wv[4 * c + 2], w3 = wv[4 * c + 3];
                    float4 h0 = hv[4 * c], h1 = hv[4 * c + 1], h2 = hv[4 * c + 2], h3 = hv[4 * c + 3];
                    float a0 = w0.x * h0.x, a1 = w2.x * h2.x;
                    a0 = fmaf(w0.y, h0.y, a0); a1 = fmaf(w2.y, h2.y, a1);
                    a0 = fmaf(w0.z, h0.z, a0); a1 = fmaf(w2.z, h2.z, a1);
                    a0 = fmaf(w0.w, h0.w, a0); a1 = fmaf(w2.w, h2.w, a1);
                    a0 = fmaf(w1.x, h1.x, a0); a1 = fmaf(w3.x, h3.x, a1);
                    a0 = fmaf(w1.y, h1.y, a0); a1 = fmaf(w3.y, h3.y, a1);
                    a0 = fmaf(w1.z, h1.z, a0); a1 = fmaf(w3.z, h3.z, a1);
                    a0 = fmaf(w1.w, h1.w, a0); a1 = fmaf(w3.w, h3.w, a1);
                    accv[c] = a0 + a1;
                }
            }
            float p1 = accv[0] + accv[1];
            float p2 = accv[2] + accv[3];
            float part = p1 + p2;                       // ((s0+s1)+(s2+s3))
            float tot = part + __shfl_xor(part, 32);    // + ((s4+s5)+(s6+s7))
            float gval = 0.0f;
            if (oo < 13 && hh == 0) {
                float raw = tot + sbhead[oo];
                if (oo < 8) {
                    gval = fmaf(2.99f, sigf(raw), 0.01f);
                    out[OFF_R + ((size_t)(b0 + rh) * KST + k) * 8 + oo] = gval;
                } else {
                    gval = 3.0f * sigf(raw);
                    out[OFF_D + ((size_t)(b0 + rh) * KST + k) * 5 + (oo - 8)] = gval;
                }
            }

            // ----- y_jump on M lanes (all data via in-wave shfl) -----
            float u0x = __shfl(ukr.x, mr * 16), u0y = __shfl(ukr.y, mr * 16);
            float u0z = __shfl(ukr.z, mr * 16), u0w = __shfl(ukr.w, mr * 16);
            float dtv = __shfl(dtr, mr * 16);
            float dhj = __shfl(gval, mr * 16 + 8 + mj);
            float yj  = __shfl(yreg, mr * 16 + mj);
            float jmp = u0x * sU2Y[mj];
            jmp = fmaf(u0y, sU2Y[5 + mj], jmp);
            jmp = fmaf(u0z, sU2Y[10 + mj], jmp);
            jmp = fmaf(u0w, sU2Y[15 + mj], jmp);
            float yjv = yj + jmp + dhj;

            // ----- build M (one RK4 substep, exact; v12-proven) -----
            float kf1 = __shfl(gval, mr * 16 + 0);
            float kf2 = __shfl(gval, mr * 16 + 1);
            float kf3 = __shfl(gval, mr * 16 + 2);
            float kf4 = __shfl(gval, mr * 16 + 3);
            float kr1 = __shfl(gval, mr * 16 + 4);
            float kr2 = __shfl(gval, mr * 16 + 5);
            float kr3 = __shfl(gval, mr * 16 + 6);
            float kr4 = __shfl(gval, mr * 16 + 7);
            const float hstep = dtv * 0.1f;
            const float d1 = kr1 + kf2, d2 = kr2 + kf3, d3 = kr3 + kf4;
            float v0 = (mj == 0) ? 1.f : 0.f;
            float v1 = (mj == 1) ? 1.f : 0.f;
            float v2 = (mj == 2) ? 1.f : 0.f;
            float v3 = (mj == 3) ? 1.f : 0.f;
            float v4 = (mj == 4) ? 1.f : 0.f;
            float a0 = v0, a1 = v1, a2 = v2, a3 = v3, a4 = v4;
#pragma unroll
            for (int s = 1; s <= 4; s++) {
                const float hsf = hstep * ((s == 1) ? 1.0f : (s == 2) ? 0.5f
                                          : (s == 3) ? (1.0f / 3.0f) : 0.25f);
                float t0 = kr1 * v1 - kf1 * v0;
                float t1 = fmaf(kf1, v0, fmaf(kr2, v2, -d1 * v1));
                float t2 = fmaf(kf2, v1, fmaf(kr3, v3, -d2 * v2));
                float t3 = fmaf(kf3, v2, fmaf(kr4, v4, -d3 * v3));
                float t4 = kf4 * v3 - kr4 * v4;
                v0 = t0 * hsf; v1 = t1 * hsf; v2 = t2 * hsf; v3 = t3 * hsf; v4 = t4 * hsf;
                a0 += v0; a1 += v1; a2 += v2; a3 += v3; a4 += v4;
            }
            float m = a0;
            m = (mi == 1) ? a1 : m;
            m = (mi == 2) ? a2 : m;
            m = (mi == 3) ? a3 : m;
            m = (mi == 4) ? a4 : m;

            // ----- M^10 = ((M^2)^2 * M)^2 via lane-parallel 5x5 matmuls -----
            auto matmul = [&](float A, float B) -> float {
                float c = 0.0f;
#pragma unroll
                for (int kk = 0; kk < 5; kk++) {
                    float av = __shfl(A, rowBase + kk);
                    float bv = __shfl(B, colBase + 5 * kk);
                    c = fmaf(av, bv, c);
                }
                return c;
            };
            float m2  = matmul(m, m);
            float m4  = matmul(m2, m2);
            float m5  = matmul(m4, m);
            float m10 = matmul(m5, m5);

            // ----- y_out = M^10 * y_jump; clamp (no-op) kept for safety -----
            float p = m10 * yjv;
            float sum = __shfl(p, rowBase + 0);
            sum += __shfl(p, rowBase + 1);
            sum += __shfl(p, rowBase + 2);
            sum += __shfl(p, rowBase + 3);
            sum += __shfl(p, rowBase + 4);
            float ynew = fmaxf(sum, 0.0f);

            // scatter back to home layout (lane rh*16+i <- lane rh*32+i*5)
            yreg = __shfl(ynew, rh * 32 + ri * 5);
            if (lane < 32 && ri < 5)
                out[((size_t)(b0 + rh) * KST + k) * 5 + ri] = yreg;
            do_lift(un0, un1, yreg);                     // lift(k+1), y via shfl
        }
        __syncthreads();

        // ---------- Ψ3: gi(k+1) ----------
        do_gi();
        __syncthreads();
    }
}

}  // namespace

extern "C" void kernel_launch(void* const* d_in, const int* in_sizes, int n_in,
                              void* d_out, int out_size, void* d_ws, size_t ws_size,
                              hipStream_t stream) {
    const float* y0     = (const float*)d_in[0];
    const float* u_seq  = (const float*)d_in[1];
    const float* dt_seq = (const float*)d_in[2];
    const float* W_lift = (const float*)d_in[3];
    const float* b_lift = (const float*)d_in[4];
    const float* W_ih   = (const float*)d_in[5];
    const float* W_hh   = (const float*)d_in[6];
    const float* b_ih   = (const float*)d_in[7];
    const float* b_hh   = (const float*)d_in[8];
    const float* W_head = (const float*)d_in[9];
    const float* b_head = (const float*)d_in[10];
    const float* u2y    = (const float*)d_in[11];
    float* out = (float*)d_out;

    rnn_v16<<<256, 768, 0, stream>>>(y0, u_seq, dt_seq, W_lift, b_lift,
                                     W_ih, W_hh, b_ih, b_hh, W_head, b_head,
                                     u2y, out);
}